// Round 1
// baseline (1228.488 us; speedup 1.0000x reference)
//
#include <hip/hip_runtime.h>
#include <cstdint>
#include <cstddef>
#include <math.h>

#define N_NODES 100000
#define N_EDGES 1600000
#define DIM 128
#define DOUT 40
#define BN_EPS 1e-5f

// ---------------- CSR build ----------------
__global__ void k_count(const int* __restrict__ ei, int* __restrict__ counts) {
    int i = blockIdx.x * blockDim.x + threadIdx.x;
    int stride = gridDim.x * blockDim.x;
    for (int e = i; e < N_EDGES; e += stride) {
        atomicAdd(&counts[ei[N_EDGES + e]], 1);
    }
}

// per-block scan of 1024 elements (256 threads x 4)
__global__ void k_scan1(int* __restrict__ data, int* __restrict__ bsums) {
    __shared__ int ts[256];
    int base = blockIdx.x * 1024;
    int t = threadIdx.x;
    int v[4];
    int s = 0;
#pragma unroll
    for (int i = 0; i < 4; i++) {
        int idx = base + t * 4 + i;
        v[i] = (idx < N_NODES) ? data[idx] : 0;
        s += v[i];
    }
    ts[t] = s;
    __syncthreads();
    for (int off = 1; off < 256; off <<= 1) {
        int own = ts[t];
        int add = (t >= off) ? ts[t - off] : 0;
        __syncthreads();
        ts[t] = own + add;
        __syncthreads();
    }
    int incl = ts[t];
    int excl = incl - s;
    int run = excl;
#pragma unroll
    for (int i = 0; i < 4; i++) {
        int idx = base + t * 4 + i;
        if (idx < N_NODES) data[idx] = run;
        run += v[i];
    }
    if (t == 255) bsums[blockIdx.x] = incl;  // block total
}

__global__ void k_scan2(int* bsums, int nb) {
    if (blockIdx.x == 0 && threadIdx.x == 0) {
        int run = 0;
        for (int b = 0; b < nb; b++) {
            int x = bsums[b];
            bsums[b] = run;
            run += x;
        }
    }
}

__global__ void k_scan3(int* __restrict__ data, const int* __restrict__ bsums) {
    int base = blockIdx.x * 1024;
    int add = bsums[blockIdx.x];
    int t = threadIdx.x;
#pragma unroll
    for (int i = 0; i < 4; i++) {
        int idx = base + t * 4 + i;
        if (idx < N_NODES) data[idx] += add;
    }
    if (blockIdx.x == 0 && t == 0) data[N_NODES] = N_EDGES;
}

__global__ void k_fill(const int* __restrict__ ei, const int* __restrict__ rowstart,
                       int* __restrict__ cursor, int* __restrict__ csr) {
    int i = blockIdx.x * blockDim.x + threadIdx.x;
    int stride = gridDim.x * blockDim.x;
    for (int e = i; e < N_EDGES; e += stride) {
        int s = ei[e];
        int d = ei[N_EDGES + e];
        int pos = atomicAdd(&cursor[d], 1);
        csr[rowstart[d] + pos] = s;
    }
}

// ---------------- mean aggregation (pull) ----------------
// one wave per node; lane holds 2 columns (float2)
__global__ __launch_bounds__(256) void k_agg(const float* __restrict__ cur,
                                             const int* __restrict__ rowstart,
                                             const int* __restrict__ csr,
                                             float* __restrict__ out) {
    int wid = (blockIdx.x * blockDim.x + threadIdx.x) >> 6;
    int lane = threadIdx.x & 63;
    if (wid >= N_NODES) return;
    int beg = rowstart[wid];
    int end = rowstart[wid + 1];
    float ax = 0.f, ay = 0.f;
    for (int e = beg; e < end; e++) {
        int s = csr[e];
        float2 v = *reinterpret_cast<const float2*>(cur + (size_t)s * DIM + lane * 2);
        ax += v.x;
        ay += v.y;
    }
    int deg = end - beg;
    float inv = 1.0f / (float)(deg > 1 ? deg : 1);
    float2 m;
    m.x = ax * inv;
    m.y = ay * inv;
    *reinterpret_cast<float2*>(out + (size_t)wid * DIM + lane * 2) = m;
}

// ---------------- fused GEMM: out = mean@W + cur@R + b  (N=128) ----------------
// block: 64 rows x 128 cols, 256 threads, thread owns 4 rows x 8 cols
// safe for out==mean (each block reads only its own rows of mean, writes after all reads)
__global__ __launch_bounds__(256) void k_gemm128(const float* __restrict__ mean,
                                                 const float* __restrict__ cur,
                                                 const float* __restrict__ W,
                                                 const float* __restrict__ R,
                                                 const float* __restrict__ bias,
                                                 float* __restrict__ out) {
    __shared__ float As[64][36];   // padded row stride 36 (144B, 16B-aligned)
    __shared__ float Ws[32][128];
    int tid = threadIdx.x;
    int tx = tid & 15;   // col group: cols tx*8 .. tx*8+7
    int ty = tid >> 4;   // row group: rows ty*4 .. ty*4+3
    float acc[4][8];
#pragma unroll
    for (int i = 0; i < 4; i++)
#pragma unroll
        for (int j = 0; j < 8; j++) acc[i][j] = 0.f;

    int row0 = blockIdx.x * 64;
    int lr = tid >> 2;         // A-load row 0..63
    int lk = (tid & 3) * 8;    // A-load k offset 0,8,16,24
    int wr = tid >> 3;         // W-load row 0..31
    int wc = (tid & 7) * 16;   // W-load col 0..112

    for (int phase = 0; phase < 2; ++phase) {
        const float* Asrc = phase ? cur : mean;
        const float* Wsrc = phase ? R : W;
        for (int k0 = 0; k0 < DIM; k0 += 32) {
            __syncthreads();
            // stage A tile: rows row0..row0+63, k = k0..k0+31
            float4 a0 = {0, 0, 0, 0}, a1 = {0, 0, 0, 0};
            int gr = row0 + lr;
            if (gr < N_NODES) {
                const float* p = Asrc + (size_t)gr * DIM + k0 + lk;
                a0 = *reinterpret_cast<const float4*>(p);
                a1 = *reinterpret_cast<const float4*>(p + 4);
            }
            *reinterpret_cast<float4*>(&As[lr][lk]) = a0;
            *reinterpret_cast<float4*>(&As[lr][lk + 4]) = a1;
            // stage W tile: rows k0..k0+31, all 128 cols
            const float* q = Wsrc + (size_t)(k0 + wr) * DIM + wc;
            *reinterpret_cast<float4*>(&Ws[wr][wc]) = *reinterpret_cast<const float4*>(q);
            *reinterpret_cast<float4*>(&Ws[wr][wc + 4]) = *reinterpret_cast<const float4*>(q + 4);
            *reinterpret_cast<float4*>(&Ws[wr][wc + 8]) = *reinterpret_cast<const float4*>(q + 8);
            *reinterpret_cast<float4*>(&Ws[wr][wc + 12]) = *reinterpret_cast<const float4*>(q + 12);
            __syncthreads();
#pragma unroll
            for (int kk = 0; kk < 32; ++kk) {
                float a[4];
#pragma unroll
                for (int i = 0; i < 4; i++) a[i] = As[ty * 4 + i][kk];
                float4 w0 = *reinterpret_cast<float4*>(&Ws[kk][tx * 8]);
                float4 w1 = *reinterpret_cast<float4*>(&Ws[kk][tx * 8 + 4]);
                float wv[8] = {w0.x, w0.y, w0.z, w0.w, w1.x, w1.y, w1.z, w1.w};
#pragma unroll
                for (int i = 0; i < 4; i++)
#pragma unroll
                    for (int j = 0; j < 8; j++) acc[i][j] += a[i] * wv[j];
            }
        }
    }
    // epilogue: + bias, store
#pragma unroll
    for (int i = 0; i < 4; i++) {
        int gr = row0 + ty * 4 + i;
        if (gr < N_NODES) {
            float4 o0, o1;
            o0.x = acc[i][0] + bias[tx * 8 + 0];
            o0.y = acc[i][1] + bias[tx * 8 + 1];
            o0.z = acc[i][2] + bias[tx * 8 + 2];
            o0.w = acc[i][3] + bias[tx * 8 + 3];
            o1.x = acc[i][4] + bias[tx * 8 + 4];
            o1.y = acc[i][5] + bias[tx * 8 + 5];
            o1.z = acc[i][6] + bias[tx * 8 + 6];
            o1.w = acc[i][7] + bias[tx * 8 + 7];
            float* po = out + (size_t)gr * DIM + tx * 8;
            *reinterpret_cast<float4*>(po) = o0;
            *reinterpret_cast<float4*>(po + 4) = o1;
        }
    }
}

// ---------------- layer-3 GEMM: out[N,40] = mean@W3 + cur@R3 + b3 ----------------
// wave per row, lanes 0..39 each own one output column; weights staged in LDS
__global__ __launch_bounds__(256) void k_gemm40(const float* __restrict__ mean,
                                                const float* __restrict__ cur,
                                                const float* __restrict__ W,
                                                const float* __restrict__ R,
                                                const float* __restrict__ bias,
                                                float* __restrict__ out) {
    __shared__ float Ws[2 * DIM][DOUT];   // 256 x 40 = 40 KB
    __shared__ float rowbuf[4][2 * DIM];  // 4 KB
    int tid = threadIdx.x;
    for (int idx = tid; idx < 2 * DIM * DOUT; idx += 256) {
        int k = idx / DOUT, j = idx % DOUT;
        Ws[k][j] = (k < DIM) ? W[k * DOUT + j] : R[(k - DIM) * DOUT + j];
    }
    int w = tid >> 6, lane = tid & 63;
    int row = blockIdx.x * 4 + w;   // grid sized exactly: 25000 blocks
    float2 mv = *reinterpret_cast<const float2*>(mean + (size_t)row * DIM + lane * 2);
    float2 cv = *reinterpret_cast<const float2*>(cur + (size_t)row * DIM + lane * 2);
    rowbuf[w][lane * 2] = mv.x;
    rowbuf[w][lane * 2 + 1] = mv.y;
    rowbuf[w][DIM + lane * 2] = cv.x;
    rowbuf[w][DIM + lane * 2 + 1] = cv.y;
    __syncthreads();
    if (lane < DOUT) {
        float acc = 0.f;
#pragma unroll 8
        for (int k = 0; k < 2 * DIM; k++) acc += rowbuf[w][k] * Ws[k][lane];
        out[(size_t)row * DOUT + lane] = acc + bias[lane];
    }
}

// ---------------- BN stats ----------------
__global__ __launch_bounds__(256) void k_colstats(const float* __restrict__ H,
                                                  float* __restrict__ sum,
                                                  float* __restrict__ sumsq) {
    int tid = threadIdx.x;
    int c = tid & 127;
    int rgrp = tid >> 7;  // 0..1
    float s = 0.f, s2 = 0.f;
    for (int r = blockIdx.x * 2 + rgrp; r < N_NODES; r += gridDim.x * 2) {
        float v = H[(size_t)r * DIM + c];
        s += v;
        s2 += v * v;
    }
    __shared__ float ls[256], ls2[256];
    ls[tid] = s;
    ls2[tid] = s2;
    __syncthreads();
    if (tid < 128) {
        s = ls[tid] + ls[tid + 128];
        s2 = ls2[tid] + ls2[tid + 128];
        atomicAdd(&sum[c], s);
        atomicAdd(&sumsq[c], s2);
    }
}

__global__ void k_bnfin(const float* __restrict__ sum, const float* __restrict__ sumsq,
                        const float* __restrict__ g, const float* __restrict__ be,
                        float* __restrict__ scale, float* __restrict__ shift) {
    int c = threadIdx.x;
    if (c < DIM) {
        float mu = sum[c] * (1.0f / N_NODES);
        float var = sumsq[c] * (1.0f / N_NODES) - mu * mu;
        float sc = g[c] * rsqrtf(var + BN_EPS);
        scale[c] = sc;
        shift[c] = be[c] - mu * sc;
    }
}

__global__ __launch_bounds__(256) void k_bnrelu(float* __restrict__ H,
                                                const float* __restrict__ scale,
                                                const float* __restrict__ shift) {
    size_t i = (size_t)blockIdx.x * blockDim.x + threadIdx.x;
    size_t stride = (size_t)gridDim.x * blockDim.x;
    size_t total = (size_t)N_NODES * DIM / 4;
    float4* H4 = reinterpret_cast<float4*>(H);
    for (; i < total; i += stride) {
        float4 v = H4[i];
        int c = (int)((i & 31) << 2);  // column of first element (row = 32 float4s)
        v.x = fmaxf(v.x * scale[c + 0] + shift[c + 0], 0.f);
        v.y = fmaxf(v.y * scale[c + 1] + shift[c + 1], 0.f);
        v.z = fmaxf(v.z * scale[c + 2] + shift[c + 2], 0.f);
        v.w = fmaxf(v.w * scale[c + 3] + shift[c + 3], 0.f);
        H4[i] = v;
    }
}

// ---------------- log_softmax over 40 cols, wave per row ----------------
__global__ __launch_bounds__(256) void k_lsm(float* __restrict__ out) {
    int wid = (blockIdx.x * blockDim.x + threadIdx.x) >> 6;
    int lane = threadIdx.x & 63;
    if (wid >= N_NODES) return;
    float v = (lane < DOUT) ? out[(size_t)wid * DOUT + lane] : -INFINITY;
    float m = v;
#pragma unroll
    for (int off = 32; off; off >>= 1) m = fmaxf(m, __shfl_xor(m, off, 64));
    float e = (lane < DOUT) ? expf(v - m) : 0.f;
    float s = e;
#pragma unroll
    for (int off = 32; off; off >>= 1) s += __shfl_xor(s, off, 64);
    if (lane < DOUT) out[(size_t)wid * DOUT + lane] = v - m - logf(s);
}

// ---------------- launch ----------------
extern "C" void kernel_launch(void* const* d_in, const int* in_sizes, int n_in,
                              void* d_out, int out_size, void* d_ws, size_t ws_size,
                              hipStream_t stream) {
    const float* x = (const float*)d_in[0];
    const int* ei = (const int*)d_in[1];
    const float* w1 = (const float*)d_in[2];
    const float* r1 = (const float*)d_in[3];
    const float* b1 = (const float*)d_in[4];
    const float* g1 = (const float*)d_in[5];
    const float* be1 = (const float*)d_in[6];
    const float* w2 = (const float*)d_in[7];
    const float* r2 = (const float*)d_in[8];
    const float* b2 = (const float*)d_in[9];
    const float* g2 = (const float*)d_in[10];
    const float* be2 = (const float*)d_in[11];
    const float* w3 = (const float*)d_in[12];
    const float* r3 = (const float*)d_in[13];
    const float* b3 = (const float*)d_in[14];
    float* out = (float*)d_out;

    // workspace layout
    float* A = (float*)d_ws;                         // 12.8M floats
    float* B = A + (size_t)N_NODES * DIM;            // 12.8M floats
    int* rowstart = (int*)(B + (size_t)N_NODES * DIM);  // N+1
    int* csr = rowstart + (N_NODES + 1);             // E
    int* cursor = csr + N_EDGES;                     // N
    int* bsums = cursor + N_NODES;                   // 128
    float* colsum = (float*)(bsums + 128);           // 128
    float* colsumsq = colsum + 128;                  // 128
    float* scaleS = colsumsq + 128;                  // 128
    float* shiftS = scaleS + 128;                    // 128
    size_t needed = (size_t)((char*)(shiftS + 128) - (char*)d_ws);
    if (ws_size < needed) return;  // not enough scratch; fail visibly

    const int SCAN_BLOCKS = (N_NODES + 1023) / 1024;  // 98

    // ---- CSR build ----
    hipMemsetAsync(rowstart, 0, sizeof(int) * (N_NODES + 1), stream);
    hipMemsetAsync(cursor, 0, sizeof(int) * N_NODES, stream);
    k_count<<<4096, 256, 0, stream>>>(ei, rowstart);
    k_scan1<<<SCAN_BLOCKS, 256, 0, stream>>>(rowstart, bsums);
    k_scan2<<<1, 64, 0, stream>>>(bsums, SCAN_BLOCKS);
    k_scan3<<<SCAN_BLOCKS, 256, 0, stream>>>(rowstart, bsums);
    k_fill<<<4096, 256, 0, stream>>>(ei, rowstart, cursor, csr);

    const int AGG_BLOCKS = N_NODES / 4;        // 25000, exact
    const int GEMM_BLOCKS = (N_NODES + 63) / 64;

    // ---- layer 1 ----
    k_agg<<<AGG_BLOCKS, 256, 0, stream>>>(x, rowstart, csr, A);
    k_gemm128<<<GEMM_BLOCKS, 256, 0, stream>>>(A, x, w1, r1, b1, A);  // in-place: A = h1
    hipMemsetAsync(colsum, 0, sizeof(float) * 256, stream);
    k_colstats<<<304, 256, 0, stream>>>(A, colsum, colsumsq);
    k_bnfin<<<1, 128, 0, stream>>>(colsum, colsumsq, g1, be1, scaleS, shiftS);
    k_bnrelu<<<2048, 256, 0, stream>>>(A, scaleS, shiftS);

    // ---- layer 2 ----
    k_agg<<<AGG_BLOCKS, 256, 0, stream>>>(A, rowstart, csr, B);
    k_gemm128<<<GEMM_BLOCKS, 256, 0, stream>>>(B, A, w2, r2, b2, B);  // in-place: B = h2
    hipMemsetAsync(colsum, 0, sizeof(float) * 256, stream);
    k_colstats<<<304, 256, 0, stream>>>(B, colsum, colsumsq);
    k_bnfin<<<1, 128, 0, stream>>>(colsum, colsumsq, g2, be2, scaleS, shiftS);
    k_bnrelu<<<2048, 256, 0, stream>>>(B, scaleS, shiftS);

    // ---- layer 3 ----
    k_agg<<<AGG_BLOCKS, 256, 0, stream>>>(B, rowstart, csr, A);
    k_gemm40<<<AGG_BLOCKS, 256, 0, stream>>>(A, B, w3, r3, b3, out);
    k_lsm<<<AGG_BLOCKS, 256, 0, stream>>>(out);
}

// Round 2
// 859.422 us; speedup vs baseline: 1.4294x; 1.4294x over previous
//
#include <hip/hip_runtime.h>
#include <cstdint>
#include <cstddef>
#include <math.h>

#define N_NODES 100000
#define N_EDGES 1600000
#define DIM 128
#define DOUT 40
#define BN_EPS 1e-5f

typedef __attribute__((ext_vector_type(8))) short bf16x8;
typedef __attribute__((ext_vector_type(4))) float f32x4;

__device__ __forceinline__ float bf2f(uint u16shifted) {
    union { uint i; float f; } c; c.i = u16shifted; return c.f;
}
__device__ __forceinline__ ushort f2bf(float f) {
    union { float f; uint i; } c; c.f = f;
    uint i = c.i;
    uint lsb = (i >> 16) & 1u;
    i += 0x7FFFu + lsb;
    return (ushort)(i >> 16);
}

// ---------------- convert x -> bf16 ----------------
__global__ __launch_bounds__(256) void k_cvt(const float* __restrict__ in,
                                             ushort* __restrict__ out, int n4) {
    int i = blockIdx.x * blockDim.x + threadIdx.x;
    int stride = gridDim.x * blockDim.x;
    for (; i < n4; i += stride) {
        float4 v = reinterpret_cast<const float4*>(in)[i];
        ushort4 o;
        o.x = f2bf(v.x); o.y = f2bf(v.y); o.z = f2bf(v.z); o.w = f2bf(v.w);
        reinterpret_cast<ushort4*>(out)[i] = o;
    }
}

// ---------------- build Wcat[n][k] = k<128 ? W[k][n] : R[k-128][n], bf16, zero-pad n>=NW ----
__global__ void k_wcat(const float* __restrict__ W, const float* __restrict__ R,
                       ushort* __restrict__ out, int NW) {
    int idx = blockIdx.x * 256 + threadIdx.x;  // grid = Nout blocks
    int n = idx >> 8, k = idx & 255;
    float v = 0.f;
    if (n < NW) v = (k < 128) ? W[k * NW + n] : R[(k - 128) * NW + n];
    out[idx] = f2bf(v);
}

// ---------------- CSR build ----------------
__global__ void k_count(const int* __restrict__ ei, int* __restrict__ counts) {
    int i = blockIdx.x * blockDim.x + threadIdx.x;
    int stride = gridDim.x * blockDim.x;
    for (int e = i; e < N_EDGES; e += stride) atomicAdd(&counts[ei[N_EDGES + e]], 1);
}

__global__ void k_scan1(int* __restrict__ data, int* __restrict__ bsums) {
    __shared__ int ts[256];
    int base = blockIdx.x * 1024;
    int t = threadIdx.x;
    int v[4]; int s = 0;
#pragma unroll
    for (int i = 0; i < 4; i++) {
        int idx = base + t * 4 + i;
        v[i] = (idx < N_NODES) ? data[idx] : 0;
        s += v[i];
    }
    ts[t] = s; __syncthreads();
    for (int off = 1; off < 256; off <<= 1) {
        int own = ts[t];
        int add = (t >= off) ? ts[t - off] : 0;
        __syncthreads();
        ts[t] = own + add;
        __syncthreads();
    }
    int incl = ts[t];
    int run = incl - s;
#pragma unroll
    for (int i = 0; i < 4; i++) {
        int idx = base + t * 4 + i;
        if (idx < N_NODES) data[idx] = run;
        run += v[i];
    }
    if (t == 255) bsums[blockIdx.x] = incl;
}

__global__ void k_scan2(int* bsums, int nb) {
    if (threadIdx.x == 0) {
        int run = 0;
        for (int b = 0; b < nb; b++) { int x = bsums[b]; bsums[b] = run; run += x; }
    }
}

__global__ void k_scan3(int* __restrict__ data, const int* __restrict__ bsums) {
    int base = blockIdx.x * 1024;
    int add = bsums[blockIdx.x];
    int t = threadIdx.x;
#pragma unroll
    for (int i = 0; i < 4; i++) {
        int idx = base + t * 4 + i;
        if (idx < N_NODES) data[idx] += add;
    }
    if (blockIdx.x == 0 && t == 0) data[N_NODES] = N_EDGES;
}

__global__ void k_fill(const int* __restrict__ ei, const int* __restrict__ rowstart,
                       int* __restrict__ cursor, int* __restrict__ csr) {
    int i = blockIdx.x * blockDim.x + threadIdx.x;
    int stride = gridDim.x * blockDim.x;
    for (int e = i; e < N_EDGES; e += stride) {
        int s = ei[e];
        int d = ei[N_EDGES + e];
        int pos = atomicAdd(&cursor[d], 1);
        csr[rowstart[d] + pos] = s;
    }
}

// ---------------- mean aggregation, bf16 (one wave per node, lane = 2 cols) ----------------
__global__ __launch_bounds__(256) void k_agg_bf(const ushort* __restrict__ cur,
                                                const int* __restrict__ rowstart,
                                                const int* __restrict__ csr,
                                                ushort* __restrict__ out) {
    int wid = (blockIdx.x * blockDim.x + threadIdx.x) >> 6;
    int lane = threadIdx.x & 63;
    if (wid >= N_NODES) return;
    int beg = rowstart[wid];
    int end = rowstart[wid + 1];
    const uint* base = reinterpret_cast<const uint*>(cur);
    float ax = 0.f, ay = 0.f;
    for (int e = beg; e < end; e++) {
        int s = csr[e];
        uint u = base[(size_t)s * 64 + lane];
        ax += bf2f(u << 16);
        ay += bf2f(u & 0xFFFF0000u);
    }
    int deg = end - beg;
    float inv = 1.0f / (float)(deg > 1 ? deg : 1);
    uint o = (uint)f2bf(ax * inv) | ((uint)f2bf(ay * inv) << 16);
    reinterpret_cast<uint*>(out)[(size_t)wid * 64 + lane] = o;
}

// ---------------- MFMA GEMM: out[M,128] = mean@W + cur@R + b (bf16 in, bf16 out) ------------
// 128x128 tile, 256 threads = 4 waves as 2x2, each wave 64x64 (4x4 frags of 16x16x32)
// in-place safe for out==mean (block reads only its own rows; writes in epilogue)
__global__ __launch_bounds__(256) void k_gemm_mfma(const ushort* __restrict__ Am,
                                                   const ushort* __restrict__ Ac,
                                                   const ushort* __restrict__ Wcat, // [128][256]
                                                   const float* __restrict__ bias,
                                                   ushort* __restrict__ out) {
    __shared__ ushort As[128 * 40];  // 128 rows x 32 k, padded stride 40 (80 B)
    __shared__ ushort Bs[128 * 40];  // 128 cols x 32 k
    int tid = threadIdx.x;
    int wid = tid >> 6, lane = tid & 63;
    int wr = wid >> 1, wc = wid & 1;
    int l15 = lane & 15, lhi = lane >> 4;
    int row0 = blockIdx.x * 128;

    f32x4 acc[4][4];
#pragma unroll
    for (int m = 0; m < 4; m++)
#pragma unroll
        for (int n = 0; n < 4; n++) acc[m][n] = (f32x4){0.f, 0.f, 0.f, 0.f};

    for (int ks = 0; ks < 8; ++ks) {
        int kg = ks * 32;
        const ushort* Asrc = (kg < 128) ? Am : Ac;
        int ka = kg & 127;
        __syncthreads();
#pragma unroll
        for (int h = 0; h < 2; ++h) {
            int c = tid + h * 256;
            int row = c >> 2, q = c & 3;
            int gr = row0 + row;
            uint4 v = {0, 0, 0, 0};
            if (gr < N_NODES)
                v = *reinterpret_cast<const uint4*>(Asrc + (size_t)gr * 128 + ka + q * 8);
            *reinterpret_cast<uint4*>(&As[row * 40 + q * 8]) = v;
        }
#pragma unroll
        for (int h = 0; h < 2; ++h) {
            int c = tid + h * 256;
            int n = c >> 2, q = c & 3;
            *reinterpret_cast<uint4*>(&Bs[n * 40 + q * 8]) =
                *reinterpret_cast<const uint4*>(Wcat + n * 256 + kg + q * 8);
        }
        __syncthreads();
        bf16x8 a[4], b[4];
#pragma unroll
        for (int m = 0; m < 4; m++)
            a[m] = *reinterpret_cast<bf16x8*>(&As[(wr * 64 + m * 16 + l15) * 40 + lhi * 8]);
#pragma unroll
        for (int n = 0; n < 4; n++)
            b[n] = *reinterpret_cast<bf16x8*>(&Bs[(wc * 64 + n * 16 + l15) * 40 + lhi * 8]);
#pragma unroll
        for (int m = 0; m < 4; m++)
#pragma unroll
            for (int n = 0; n < 4; n++)
                acc[m][n] = __builtin_amdgcn_mfma_f32_16x16x32_bf16(a[m], b[n], acc[m][n], 0, 0, 0);
    }
    // epilogue: + bias, bf16 store
#pragma unroll
    for (int m = 0; m < 4; m++) {
        int rbase = row0 + wr * 64 + m * 16 + lhi * 4;
#pragma unroll
        for (int n = 0; n < 4; n++) {
            int col = wc * 64 + n * 16 + l15;
            float bv = bias[col];
#pragma unroll
            for (int j = 0; j < 4; j++) {
                int gr = rbase + j;
                if (gr < N_NODES) out[(size_t)gr * 128 + col] = f2bf(acc[m][n][j] + bv);
            }
        }
    }
}

// ---------------- layer-3 MFMA GEMM + bias + log_softmax fused ----------------
// 128 rows x 48 cols (40 padded to 48); 4 waves, wave w: rows w*32..+31 (2 frags), 3 col frags
__global__ __launch_bounds__(256) void k_gemm40_mfma(const ushort* __restrict__ Am,
                                                     const ushort* __restrict__ Ac,
                                                     const ushort* __restrict__ Wcat, // [48][256]
                                                     const float* __restrict__ bias,  // [40]
                                                     float* __restrict__ out) {
    __shared__ ushort As[128 * 40];
    __shared__ ushort Bs[48 * 40];
    int tid = threadIdx.x;
    int w = tid >> 6, lane = tid & 63;
    int l15 = lane & 15, lhi = lane >> 4;
    int row0 = blockIdx.x * 128;

    f32x4 acc[2][3];
#pragma unroll
    for (int m = 0; m < 2; m++)
#pragma unroll
        for (int n = 0; n < 3; n++) acc[m][n] = (f32x4){0.f, 0.f, 0.f, 0.f};

    for (int ks = 0; ks < 8; ++ks) {
        int kg = ks * 32;
        const ushort* Asrc = (kg < 128) ? Am : Ac;
        int ka = kg & 127;
        __syncthreads();
#pragma unroll
        for (int h = 0; h < 2; ++h) {
            int c = tid + h * 256;
            int row = c >> 2, q = c & 3;
            int gr = row0 + row;
            uint4 v = {0, 0, 0, 0};
            if (gr < N_NODES)
                v = *reinterpret_cast<const uint4*>(Asrc + (size_t)gr * 128 + ka + q * 8);
            *reinterpret_cast<uint4*>(&As[row * 40 + q * 8]) = v;
        }
        if (tid < 192) {
            int n = tid >> 2, q = tid & 3;
            *reinterpret_cast<uint4*>(&Bs[n * 40 + q * 8]) =
                *reinterpret_cast<const uint4*>(Wcat + n * 256 + kg + q * 8);
        }
        __syncthreads();
        bf16x8 a[2], b[3];
#pragma unroll
        for (int m = 0; m < 2; m++)
            a[m] = *reinterpret_cast<bf16x8*>(&As[(w * 32 + m * 16 + l15) * 40 + lhi * 8]);
#pragma unroll
        for (int n = 0; n < 3; n++)
            b[n] = *reinterpret_cast<bf16x8*>(&Bs[(n * 16 + l15) * 40 + lhi * 8]);
#pragma unroll
        for (int m = 0; m < 2; m++)
#pragma unroll
            for (int n = 0; n < 3; n++)
                acc[m][n] = __builtin_amdgcn_mfma_f32_16x16x32_bf16(a[m], b[n], acc[m][n], 0, 0, 0);
    }
    // epilogue: bias + log_softmax per row (row lives in a 16-lane group)
    float b0 = bias[l15];
    float b1 = bias[16 + l15];
    float b2 = (l15 < 8) ? bias[32 + l15] : 0.f;
#pragma unroll
    for (int m = 0; m < 2; m++) {
#pragma unroll
        for (int j = 0; j < 4; j++) {
            int grow = row0 + w * 32 + m * 16 + lhi * 4 + j;
            float v0 = acc[m][0][j] + b0;
            float v1 = acc[m][1][j] + b1;
            float v2 = (l15 < 8) ? (acc[m][2][j] + b2) : -INFINITY;
            float mx = fmaxf(fmaxf(v0, v1), v2);
#pragma unroll
            for (int off = 1; off < 16; off <<= 1) mx = fmaxf(mx, __shfl_xor(mx, off, 64));
            float s = expf(v0 - mx) + expf(v1 - mx) + ((l15 < 8) ? expf(v2 - mx) : 0.f);
#pragma unroll
            for (int off = 1; off < 16; off <<= 1) s += __shfl_xor(s, off, 64);
            float lg = mx + logf(s);
            if (grow < N_NODES) {
                out[(size_t)grow * DOUT + l15] = v0 - lg;
                out[(size_t)grow * DOUT + 16 + l15] = v1 - lg;
                if (l15 < 8) out[(size_t)grow * DOUT + 32 + l15] = v2 - lg;
            }
        }
    }
}

// ---------------- BN stats on bf16 H ----------------
__global__ __launch_bounds__(256) void k_colstats_bf(const ushort* __restrict__ H,
                                                     float* __restrict__ sum,
                                                     float* __restrict__ sumsq) {
    int tid = threadIdx.x;
    int cg = tid & 31;   // cols cg*4..cg*4+3
    int rr = tid >> 5;   // 0..7
    float s[4] = {0, 0, 0, 0}, s2[4] = {0, 0, 0, 0};
    for (int r = blockIdx.x * 8 + rr; r < N_NODES; r += gridDim.x * 8) {
        uint2 u = *reinterpret_cast<const uint2*>(H + (size_t)r * 128 + cg * 4);
        float f0 = bf2f(u.x << 16), f1 = bf2f(u.x & 0xFFFF0000u);
        float f2 = bf2f(u.y << 16), f3 = bf2f(u.y & 0xFFFF0000u);
        s[0] += f0; s2[0] += f0 * f0;
        s[1] += f1; s2[1] += f1 * f1;
        s[2] += f2; s2[2] += f2 * f2;
        s[3] += f3; s2[3] += f3 * f3;
    }
    __shared__ float ls[256][4], ls2[256][4];
#pragma unroll
    for (int i = 0; i < 4; i++) { ls[tid][i] = s[i]; ls2[tid][i] = s2[i]; }
    __syncthreads();
    if (tid < 32) {
#pragma unroll
        for (int j = 1; j < 8; j++)
#pragma unroll
            for (int i = 0; i < 4; i++) { s[i] += ls[j * 32 + tid][i]; s2[i] += ls2[j * 32 + tid][i]; }
#pragma unroll
        for (int i = 0; i < 4; i++) {
            atomicAdd(&sum[tid * 4 + i], s[i]);
            atomicAdd(&sumsq[tid * 4 + i], s2[i]);
        }
    }
}

__global__ void k_bnfin(const float* __restrict__ sum, const float* __restrict__ sumsq,
                        const float* __restrict__ g, const float* __restrict__ be,
                        float* __restrict__ scale, float* __restrict__ shift) {
    int c = threadIdx.x;
    if (c < DIM) {
        float mu = sum[c] * (1.0f / N_NODES);
        float var = sumsq[c] * (1.0f / N_NODES) - mu * mu;
        float sc = g[c] * rsqrtf(var + BN_EPS);
        scale[c] = sc;
        shift[c] = be[c] - mu * sc;
    }
}

// ---------------- BN apply + ReLU, bf16 in-place ----------------
__global__ __launch_bounds__(256) void k_bnrelu_bf(ushort* __restrict__ H,
                                                   const float* __restrict__ scale,
                                                   const float* __restrict__ shift) {
    __shared__ float sc[128], sh[128];
    int tid = threadIdx.x;
    if (tid < 128) { sc[tid] = scale[tid]; sh[tid] = shift[tid]; }
    __syncthreads();
    int i = blockIdx.x * blockDim.x + tid;
    int stride = gridDim.x * blockDim.x;
    int total = N_NODES * (DIM / 4);  // uint2 units
    uint2* H2 = reinterpret_cast<uint2*>(H);
    for (; i < total; i += stride) {
        uint2 u = H2[i];
        int c = (i & 31) * 4;
        float f0 = fmaxf(bf2f(u.x << 16) * sc[c + 0] + sh[c + 0], 0.f);
        float f1 = fmaxf(bf2f(u.x & 0xFFFF0000u) * sc[c + 1] + sh[c + 1], 0.f);
        float f2 = fmaxf(bf2f(u.y << 16) * sc[c + 2] + sh[c + 2], 0.f);
        float f3 = fmaxf(bf2f(u.y & 0xFFFF0000u) * sc[c + 3] + sh[c + 3], 0.f);
        u.x = (uint)f2bf(f0) | ((uint)f2bf(f1) << 16);
        u.y = (uint)f2bf(f2) | ((uint)f2bf(f3) << 16);
        H2[i] = u;
    }
}

// ---------------- launch ----------------
extern "C" void kernel_launch(void* const* d_in, const int* in_sizes, int n_in,
                              void* d_out, int out_size, void* d_ws, size_t ws_size,
                              hipStream_t stream) {
    const float* x = (const float*)d_in[0];
    const int* ei = (const int*)d_in[1];
    const float* w1 = (const float*)d_in[2];
    const float* r1 = (const float*)d_in[3];
    const float* b1 = (const float*)d_in[4];
    const float* g1 = (const float*)d_in[5];
    const float* be1 = (const float*)d_in[6];
    const float* w2 = (const float*)d_in[7];
    const float* r2 = (const float*)d_in[8];
    const float* b2 = (const float*)d_in[9];
    const float* g2 = (const float*)d_in[10];
    const float* be2 = (const float*)d_in[11];
    const float* w3 = (const float*)d_in[12];
    const float* r3 = (const float*)d_in[13];
    const float* b3 = (const float*)d_in[14];
    float* out = (float*)d_out;

    const size_t NF = (size_t)N_NODES * DIM;  // 12.8M
    ushort* Xb = (ushort*)d_ws;
    ushort* Ab = Xb + NF;
    ushort* Bb = Ab + NF;
    ushort* Wc1 = Bb + NF;             // 128*256
    ushort* Wc2 = Wc1 + 128 * 256;
    ushort* Wc3 = Wc2 + 128 * 256;     // 48*256
    int* rowstart = (int*)(Wc3 + 48 * 256);
    int* csr = rowstart + (N_NODES + 1);
    int* cursor = csr + N_EDGES;
    int* bsums = cursor + N_NODES;
    float* colsum = (float*)(bsums + 128);
    float* colsumsq = colsum + 128;
    float* scaleS = colsumsq + 128;
    float* shiftS = scaleS + 128;
    size_t needed = (size_t)((char*)(shiftS + 128) - (char*)d_ws);
    if (ws_size < needed) return;

    const int SCAN_BLOCKS = (N_NODES + 1023) / 1024;  // 98
    const int AGG_BLOCKS = N_NODES / 4;               // 25000
    const int GEMM_BLOCKS = (N_NODES + 127) / 128;    // 782

    // conversions
    k_cvt<<<2048, 256, 0, stream>>>(x, Xb, (int)(NF / 4));
    k_wcat<<<128, 256, 0, stream>>>(w1, r1, Wc1, 128);
    k_wcat<<<128, 256, 0, stream>>>(w2, r2, Wc2, 128);
    k_wcat<<<48, 256, 0, stream>>>(w3, r3, Wc3, DOUT);

    // CSR build
    hipMemsetAsync(rowstart, 0, sizeof(int) * (N_NODES + 1), stream);
    hipMemsetAsync(cursor, 0, sizeof(int) * N_NODES, stream);
    k_count<<<4096, 256, 0, stream>>>(ei, rowstart);
    k_scan1<<<SCAN_BLOCKS, 256, 0, stream>>>(rowstart, bsums);
    k_scan2<<<1, 64, 0, stream>>>(bsums, SCAN_BLOCKS);
    k_scan3<<<SCAN_BLOCKS, 256, 0, stream>>>(rowstart, bsums);
    k_fill<<<4096, 256, 0, stream>>>(ei, rowstart, cursor, csr);

    // ---- layer 1 ----
    k_agg_bf<<<AGG_BLOCKS, 256, 0, stream>>>(Xb, rowstart, csr, Ab);
    k_gemm_mfma<<<GEMM_BLOCKS, 256, 0, stream>>>(Ab, Xb, Wc1, b1, Ab);
    hipMemsetAsync(colsum, 0, sizeof(float) * 256, stream);
    k_colstats_bf<<<304, 256, 0, stream>>>(Ab, colsum, colsumsq);
    k_bnfin<<<1, 128, 0, stream>>>(colsum, colsumsq, g1, be1, scaleS, shiftS);
    k_bnrelu_bf<<<2048, 256, 0, stream>>>(Ab, scaleS, shiftS);

    // ---- layer 2 ----
    k_agg_bf<<<AGG_BLOCKS, 256, 0, stream>>>(Ab, rowstart, csr, Bb);
    k_gemm_mfma<<<GEMM_BLOCKS, 256, 0, stream>>>(Bb, Ab, Wc2, b2, Bb);
    hipMemsetAsync(colsum, 0, sizeof(float) * 256, stream);
    k_colstats_bf<<<304, 256, 0, stream>>>(Bb, colsum, colsumsq);
    k_bnfin<<<1, 128, 0, stream>>>(colsum, colsumsq, g2, be2, scaleS, shiftS);
    k_bnrelu_bf<<<2048, 256, 0, stream>>>(Bb, scaleS, shiftS);

    // ---- layer 3 (bias + log_softmax fused) ----
    k_agg_bf<<<AGG_BLOCKS, 256, 0, stream>>>(Bb, rowstart, csr, Ab);
    k_gemm40_mfma<<<GEMM_BLOCKS, 256, 0, stream>>>(Ab, Bb, Wc3, b3, out);
}

// Round 3
// 593.744 us; speedup vs baseline: 2.0691x; 1.4475x over previous
//
#include <hip/hip_runtime.h>
#include <cstdint>
#include <cstddef>
#include <math.h>

#define N_NODES 100000
#define N_EDGES 1600000
#define DIM 128
#define DOUT 40
#define BN_EPS 1e-5f

typedef __attribute__((ext_vector_type(8))) short bf16x8;
typedef __attribute__((ext_vector_type(4))) float f32x4;

__device__ __forceinline__ float bf2f(uint u16shifted) {
    union { uint i; float f; } c; c.i = u16shifted; return c.f;
}
__device__ __forceinline__ ushort f2bf(float f) {
    union { float f; uint i; } c; c.f = f;
    uint i = c.i;
    uint lsb = (i >> 16) & 1u;
    i += 0x7FFFu + lsb;
    return (ushort)(i >> 16);
}

// ---------------- convert x -> bf16 ----------------
__global__ __launch_bounds__(256) void k_cvt(const float* __restrict__ in,
                                             ushort* __restrict__ out, int n4) {
    int i = blockIdx.x * blockDim.x + threadIdx.x;
    int stride = gridDim.x * blockDim.x;
    for (; i < n4; i += stride) {
        float4 v = reinterpret_cast<const float4*>(in)[i];
        ushort4 o;
        o.x = f2bf(v.x); o.y = f2bf(v.y); o.z = f2bf(v.z); o.w = f2bf(v.w);
        reinterpret_cast<ushort4*>(out)[i] = o;
    }
}

// ---------------- build Wcat[n][k] = k<128 ? W[k][n] : R[k-128][n], bf16, zero-pad n>=NW ----
__global__ void k_wcat(const float* __restrict__ W, const float* __restrict__ R,
                       ushort* __restrict__ out, int NW) {
    int idx = blockIdx.x * 256 + threadIdx.x;  // grid = Nout blocks
    int n = idx >> 8, k = idx & 255;
    float v = 0.f;
    if (n < NW) v = (k < 128) ? W[k * NW + n] : R[(k - 128) * NW + n];
    out[idx] = f2bf(v);
}

// ---------------- CSR build ----------------
__global__ void k_count(const int* __restrict__ ei, int* __restrict__ counts) {
    int i = blockIdx.x * blockDim.x + threadIdx.x;
    int stride = gridDim.x * blockDim.x;
    for (int e = i; e < N_EDGES; e += stride) atomicAdd(&counts[ei[N_EDGES + e]], 1);
}

__global__ void k_scan1(int* __restrict__ data, int* __restrict__ bsums) {
    __shared__ int ts[256];
    int base = blockIdx.x * 1024;
    int t = threadIdx.x;
    int v[4]; int s = 0;
#pragma unroll
    for (int i = 0; i < 4; i++) {
        int idx = base + t * 4 + i;
        v[i] = (idx < N_NODES) ? data[idx] : 0;
        s += v[i];
    }
    ts[t] = s; __syncthreads();
    for (int off = 1; off < 256; off <<= 1) {
        int own = ts[t];
        int add = (t >= off) ? ts[t - off] : 0;
        __syncthreads();
        ts[t] = own + add;
        __syncthreads();
    }
    int incl = ts[t];
    int run = incl - s;
#pragma unroll
    for (int i = 0; i < 4; i++) {
        int idx = base + t * 4 + i;
        if (idx < N_NODES) data[idx] = run;
        run += v[i];
    }
    if (t == 255) bsums[blockIdx.x] = incl;
}

__global__ void k_scan2(int* bsums, int nb) {
    if (threadIdx.x == 0) {
        int run = 0;
        for (int b = 0; b < nb; b++) { int x = bsums[b]; bsums[b] = run; run += x; }
    }
}

__global__ void k_scan3(int* __restrict__ data, const int* __restrict__ bsums) {
    int base = blockIdx.x * 1024;
    int add = bsums[blockIdx.x];
    int t = threadIdx.x;
#pragma unroll
    for (int i = 0; i < 4; i++) {
        int idx = base + t * 4 + i;
        if (idx < N_NODES) data[idx] += add;
    }
    if (blockIdx.x == 0 && t == 0) data[N_NODES] = N_EDGES;
}

__global__ void k_fill(const int* __restrict__ ei, const int* __restrict__ rowstart,
                       int* __restrict__ cursor, int* __restrict__ csr) {
    int i = blockIdx.x * blockDim.x + threadIdx.x;
    int stride = gridDim.x * blockDim.x;
    for (int e = i; e < N_EDGES; e += stride) {
        int s = ei[e];
        int d = ei[N_EDGES + e];
        int pos = atomicAdd(&cursor[d], 1);
        csr[rowstart[d] + pos] = s;
    }
}

// ---------------- mean aggregation, bf16, 4 edges in flight ----------------
// one wave per node; lane = slot(0..3) x colgroup(0..15); each lane loads uint4 = 8 bf16 cols
__global__ __launch_bounds__(256) void k_agg_bf(const ushort* __restrict__ cur,
                                                const int* __restrict__ rowstart,
                                                const int* __restrict__ csr,
                                                ushort* __restrict__ out) {
    int wid = (blockIdx.x * blockDim.x + threadIdx.x) >> 6;
    int lane = threadIdx.x & 63;
    if (wid >= N_NODES) return;
    int beg = rowstart[wid];
    int end = rowstart[wid + 1];
    int slot = lane >> 4;   // which edge within a group of 4
    int cg = lane & 15;     // column group: cols cg*8 .. cg*8+7
    const uint4* base = reinterpret_cast<const uint4*>(cur);  // row = 16 x uint4
    float a0 = 0.f, a1 = 0.f, a2 = 0.f, a3 = 0.f, a4 = 0.f, a5 = 0.f, a6 = 0.f, a7 = 0.f;
#pragma unroll 2
    for (int e = beg + slot; e < end; e += 4) {
        int s = csr[e];
        uint4 u = base[(size_t)s * 16 + cg];
        a0 += bf2f(u.x << 16); a1 += bf2f(u.x & 0xFFFF0000u);
        a2 += bf2f(u.y << 16); a3 += bf2f(u.y & 0xFFFF0000u);
        a4 += bf2f(u.z << 16); a5 += bf2f(u.z & 0xFFFF0000u);
        a6 += bf2f(u.w << 16); a7 += bf2f(u.w & 0xFFFF0000u);
    }
    // combine the 4 slots: lanes l, l^16, l^32
#pragma unroll
    for (int off = 16; off < 64; off <<= 1) {
        a0 += __shfl_xor(a0, off, 64); a1 += __shfl_xor(a1, off, 64);
        a2 += __shfl_xor(a2, off, 64); a3 += __shfl_xor(a3, off, 64);
        a4 += __shfl_xor(a4, off, 64); a5 += __shfl_xor(a5, off, 64);
        a6 += __shfl_xor(a6, off, 64); a7 += __shfl_xor(a7, off, 64);
    }
    if (slot == 0) {
        int deg = end - beg;
        float inv = 1.0f / (float)(deg > 1 ? deg : 1);
        uint4 o;
        o.x = (uint)f2bf(a0 * inv) | ((uint)f2bf(a1 * inv) << 16);
        o.y = (uint)f2bf(a2 * inv) | ((uint)f2bf(a3 * inv) << 16);
        o.z = (uint)f2bf(a4 * inv) | ((uint)f2bf(a5 * inv) << 16);
        o.w = (uint)f2bf(a6 * inv) | ((uint)f2bf(a7 * inv) << 16);
        reinterpret_cast<uint4*>(out)[(size_t)wid * 16 + cg] = o;
    }
}

// ---------------- MFMA GEMM: out[M,128] = mean@W + cur@R + b (bf16 in, bf16 out) ------------
// 128x128 tile, 256 threads = 4 waves as 2x2, each wave 64x64 (4x4 frags of 16x16x32)
// in-place safe for out==mean (block reads only its own rows; writes in epilogue)
__global__ __launch_bounds__(256) void k_gemm_mfma(const ushort* __restrict__ Am,
                                                   const ushort* __restrict__ Ac,
                                                   const ushort* __restrict__ Wcat, // [128][256]
                                                   const float* __restrict__ bias,
                                                   ushort* __restrict__ out) {
    __shared__ ushort As[128 * 40];  // 128 rows x 32 k, padded stride 40 (80 B)
    __shared__ ushort Bs[128 * 40];  // 128 cols x 32 k
    int tid = threadIdx.x;
    int wid = tid >> 6, lane = tid & 63;
    int wr = wid >> 1, wc = wid & 1;
    int l15 = lane & 15, lhi = lane >> 4;
    int row0 = blockIdx.x * 128;

    f32x4 acc[4][4];
#pragma unroll
    for (int m = 0; m < 4; m++)
#pragma unroll
        for (int n = 0; n < 4; n++) acc[m][n] = (f32x4){0.f, 0.f, 0.f, 0.f};

    for (int ks = 0; ks < 8; ++ks) {
        int kg = ks * 32;
        const ushort* Asrc = (kg < 128) ? Am : Ac;
        int ka = kg & 127;
        __syncthreads();
#pragma unroll
        for (int h = 0; h < 2; ++h) {
            int c = tid + h * 256;
            int row = c >> 2, q = c & 3;
            int gr = row0 + row;
            uint4 v = {0, 0, 0, 0};
            if (gr < N_NODES)
                v = *reinterpret_cast<const uint4*>(Asrc + (size_t)gr * 128 + ka + q * 8);
            *reinterpret_cast<uint4*>(&As[row * 40 + q * 8]) = v;
        }
#pragma unroll
        for (int h = 0; h < 2; ++h) {
            int c = tid + h * 256;
            int n = c >> 2, q = c & 3;
            *reinterpret_cast<uint4*>(&Bs[n * 40 + q * 8]) =
                *reinterpret_cast<const uint4*>(Wcat + n * 256 + kg + q * 8);
        }
        __syncthreads();
        bf16x8 a[4], b[4];
#pragma unroll
        for (int m = 0; m < 4; m++)
            a[m] = *reinterpret_cast<bf16x8*>(&As[(wr * 64 + m * 16 + l15) * 40 + lhi * 8]);
#pragma unroll
        for (int n = 0; n < 4; n++)
            b[n] = *reinterpret_cast<bf16x8*>(&Bs[(wc * 64 + n * 16 + l15) * 40 + lhi * 8]);
#pragma unroll
        for (int m = 0; m < 4; m++)
#pragma unroll
            for (int n = 0; n < 4; n++)
                acc[m][n] = __builtin_amdgcn_mfma_f32_16x16x32_bf16(a[m], b[n], acc[m][n], 0, 0, 0);
    }
    // epilogue: + bias, bf16 store
#pragma unroll
    for (int m = 0; m < 4; m++) {
        int rbase = row0 + wr * 64 + m * 16 + lhi * 4;
#pragma unroll
        for (int n = 0; n < 4; n++) {
            int col = wc * 64 + n * 16 + l15;
            float bv = bias[col];
#pragma unroll
            for (int j = 0; j < 4; j++) {
                int gr = rbase + j;
                if (gr < N_NODES) out[(size_t)gr * 128 + col] = f2bf(acc[m][n][j] + bv);
            }
        }
    }
}

// ---------------- layer-3 MFMA GEMM + bias + log_softmax fused ----------------
// 128 rows x 48 cols (40 padded to 48); 4 waves, wave w: rows w*32..+31 (2 frags), 3 col frags
__global__ __launch_bounds__(256) void k_gemm40_mfma(const ushort* __restrict__ Am,
                                                     const ushort* __restrict__ Ac,
                                                     const ushort* __restrict__ Wcat, // [48][256]
                                                     const float* __restrict__ bias,  // [40]
                                                     float* __restrict__ out) {
    __shared__ ushort As[128 * 40];
    __shared__ ushort Bs[48 * 40];
    int tid = threadIdx.x;
    int w = tid >> 6, lane = tid & 63;
    int l15 = lane & 15, lhi = lane >> 4;
    int row0 = blockIdx.x * 128;

    f32x4 acc[2][3];
#pragma unroll
    for (int m = 0; m < 2; m++)
#pragma unroll
        for (int n = 0; n < 3; n++) acc[m][n] = (f32x4){0.f, 0.f, 0.f, 0.f};

    for (int ks = 0; ks < 8; ++ks) {
        int kg = ks * 32;
        const ushort* Asrc = (kg < 128) ? Am : Ac;
        int ka = kg & 127;
        __syncthreads();
#pragma unroll
        for (int h = 0; h < 2; ++h) {
            int c = tid + h * 256;
            int row = c >> 2, q = c & 3;
            int gr = row0 + row;
            uint4 v = {0, 0, 0, 0};
            if (gr < N_NODES)
                v = *reinterpret_cast<const uint4*>(Asrc + (size_t)gr * 128 + ka + q * 8);
            *reinterpret_cast<uint4*>(&As[row * 40 + q * 8]) = v;
        }
        if (tid < 192) {
            int n = tid >> 2, q = tid & 3;
            *reinterpret_cast<uint4*>(&Bs[n * 40 + q * 8]) =
                *reinterpret_cast<const uint4*>(Wcat + n * 256 + kg + q * 8);
        }
        __syncthreads();
        bf16x8 a[2], b[3];
#pragma unroll
        for (int m = 0; m < 2; m++)
            a[m] = *reinterpret_cast<bf16x8*>(&As[(w * 32 + m * 16 + l15) * 40 + lhi * 8]);
#pragma unroll
        for (int n = 0; n < 3; n++)
            b[n] = *reinterpret_cast<bf16x8*>(&Bs[(n * 16 + l15) * 40 + lhi * 8]);
#pragma unroll
        for (int m = 0; m < 2; m++)
#pragma unroll
            for (int n = 0; n < 3; n++)
                acc[m][n] = __builtin_amdgcn_mfma_f32_16x16x32_bf16(a[m], b[n], acc[m][n], 0, 0, 0);
    }
    // epilogue: bias + log_softmax per row (row lives in a 16-lane group)
    float b0 = bias[l15];
    float b1 = bias[16 + l15];
    float b2 = (l15 < 8) ? bias[32 + l15] : 0.f;
#pragma unroll
    for (int m = 0; m < 2; m++) {
#pragma unroll
        for (int j = 0; j < 4; j++) {
            int grow = row0 + w * 32 + m * 16 + lhi * 4 + j;
            float v0 = acc[m][0][j] + b0;
            float v1 = acc[m][1][j] + b1;
            float v2 = (l15 < 8) ? (acc[m][2][j] + b2) : -INFINITY;
            float mx = fmaxf(fmaxf(v0, v1), v2);
#pragma unroll
            for (int off = 1; off < 16; off <<= 1) mx = fmaxf(mx, __shfl_xor(mx, off, 64));
            float s = expf(v0 - mx) + expf(v1 - mx) + ((l15 < 8) ? expf(v2 - mx) : 0.f);
#pragma unroll
            for (int off = 1; off < 16; off <<= 1) s += __shfl_xor(s, off, 64);
            float lg = mx + logf(s);
            if (grow < N_NODES) {
                out[(size_t)grow * DOUT + l15] = v0 - lg;
                out[(size_t)grow * DOUT + 16 + l15] = v1 - lg;
                if (l15 < 8) out[(size_t)grow * DOUT + 32 + l15] = v2 - lg;
            }
        }
    }
}

// ---------------- BN stats on bf16 H ----------------
__global__ __launch_bounds__(256) void k_colstats_bf(const ushort* __restrict__ H,
                                                     float* __restrict__ sum,
                                                     float* __restrict__ sumsq) {
    int tid = threadIdx.x;
    int cg = tid & 31;   // cols cg*4..cg*4+3
    int rr = tid >> 5;   // 0..7
    float s[4] = {0, 0, 0, 0}, s2[4] = {0, 0, 0, 0};
    for (int r = blockIdx.x * 8 + rr; r < N_NODES; r += gridDim.x * 8) {
        uint2 u = *reinterpret_cast<const uint2*>(H + (size_t)r * 128 + cg * 4);
        float f0 = bf2f(u.x << 16), f1 = bf2f(u.x & 0xFFFF0000u);
        float f2 = bf2f(u.y << 16), f3 = bf2f(u.y & 0xFFFF0000u);
        s[0] += f0; s2[0] += f0 * f0;
        s[1] += f1; s2[1] += f1 * f1;
        s[2] += f2; s2[2] += f2 * f2;
        s[3] += f3; s2[3] += f3 * f3;
    }
    __shared__ float ls[256][4], ls2[256][4];
#pragma unroll
    for (int i = 0; i < 4; i++) { ls[tid][i] = s[i]; ls2[tid][i] = s2[i]; }
    __syncthreads();
    if (tid < 32) {
#pragma unroll
        for (int j = 1; j < 8; j++)
#pragma unroll
            for (int i = 0; i < 4; i++) { s[i] += ls[j * 32 + tid][i]; s2[i] += ls2[j * 32 + tid][i]; }
#pragma unroll
        for (int i = 0; i < 4; i++) {
            atomicAdd(&sum[tid * 4 + i], s[i]);
            atomicAdd(&sumsq[tid * 4 + i], s2[i]);
        }
    }
}

__global__ void k_bnfin(const float* __restrict__ sum, const float* __restrict__ sumsq,
                        const float* __restrict__ g, const float* __restrict__ be,
                        float* __restrict__ scale, float* __restrict__ shift) {
    int c = threadIdx.x;
    if (c < DIM) {
        float mu = sum[c] * (1.0f / N_NODES);
        float var = sumsq[c] * (1.0f / N_NODES) - mu * mu;
        float sc = g[c] * rsqrtf(var + BN_EPS);
        scale[c] = sc;
        shift[c] = be[c] - mu * sc;
    }
}

// ---------------- BN apply + ReLU, bf16 in-place ----------------
__global__ __launch_bounds__(256) void k_bnrelu_bf(ushort* __restrict__ H,
                                                   const float* __restrict__ scale,
                                                   const float* __restrict__ shift) {
    __shared__ float sc[128], sh[128];
    int tid = threadIdx.x;
    if (tid < 128) { sc[tid] = scale[tid]; sh[tid] = shift[tid]; }
    __syncthreads();
    int i = blockIdx.x * blockDim.x + tid;
    int stride = gridDim.x * blockDim.x;
    int total = N_NODES * (DIM / 4);  // uint2 units
    uint2* H2 = reinterpret_cast<uint2*>(H);
    for (; i < total; i += stride) {
        uint2 u = H2[i];
        int c = (i & 31) * 4;
        float f0 = fmaxf(bf2f(u.x << 16) * sc[c + 0] + sh[c + 0], 0.f);
        float f1 = fmaxf(bf2f(u.x & 0xFFFF0000u) * sc[c + 1] + sh[c + 1], 0.f);
        float f2 = fmaxf(bf2f(u.y << 16) * sc[c + 2] + sh[c + 2], 0.f);
        float f3 = fmaxf(bf2f(u.y & 0xFFFF0000u) * sc[c + 3] + sh[c + 3], 0.f);
        u.x = (uint)f2bf(f0) | ((uint)f2bf(f1) << 16);
        u.y = (uint)f2bf(f2) | ((uint)f2bf(f3) << 16);
        H2[i] = u;
    }
}

// ---------------- launch ----------------
extern "C" void kernel_launch(void* const* d_in, const int* in_sizes, int n_in,
                              void* d_out, int out_size, void* d_ws, size_t ws_size,
                              hipStream_t stream) {
    const float* x = (const float*)d_in[0];
    const int* ei = (const int*)d_in[1];
    const float* w1 = (const float*)d_in[2];
    const float* r1 = (const float*)d_in[3];
    const float* b1 = (const float*)d_in[4];
    const float* g1 = (const float*)d_in[5];
    const float* be1 = (const float*)d_in[6];
    const float* w2 = (const float*)d_in[7];
    const float* r2 = (const float*)d_in[8];
    const float* b2 = (const float*)d_in[9];
    const float* g2 = (const float*)d_in[10];
    const float* be2 = (const float*)d_in[11];
    const float* w3 = (const float*)d_in[12];
    const float* r3 = (const float*)d_in[13];
    const float* b3 = (const float*)d_in[14];
    float* out = (float*)d_out;

    const size_t NF = (size_t)N_NODES * DIM;  // 12.8M
    ushort* Xb = (ushort*)d_ws;
    ushort* Ab = Xb + NF;
    ushort* Bb = Ab + NF;
    ushort* Wc1 = Bb + NF;             // 128*256
    ushort* Wc2 = Wc1 + 128 * 256;
    ushort* Wc3 = Wc2 + 128 * 256;     // 48*256
    int* rowstart = (int*)(Wc3 + 48 * 256);
    int* csr = rowstart + (N_NODES + 1);
    int* cursor = csr + N_EDGES;
    int* bsums = cursor + N_NODES;
    float* colsum = (float*)(bsums + 128);
    float* colsumsq = colsum + 128;
    float* scaleS = colsumsq + 128;
    float* shiftS = scaleS + 128;
    size_t needed = (size_t)((char*)(shiftS + 128) - (char*)d_ws);
    if (ws_size < needed) return;

    const int SCAN_BLOCKS = (N_NODES + 1023) / 1024;  // 98
    const int AGG_BLOCKS = N_NODES / 4;               // 25000
    const int GEMM_BLOCKS = (N_NODES + 127) / 128;    // 782

    // conversions
    k_cvt<<<2048, 256, 0, stream>>>(x, Xb, (int)(NF / 4));
    k_wcat<<<128, 256, 0, stream>>>(w1, r1, Wc1, 128);
    k_wcat<<<128, 256, 0, stream>>>(w2, r2, Wc2, 128);
    k_wcat<<<48, 256, 0, stream>>>(w3, r3, Wc3, DOUT);

    // CSR build
    hipMemsetAsync(rowstart, 0, sizeof(int) * (N_NODES + 1), stream);
    hipMemsetAsync(cursor, 0, sizeof(int) * N_NODES, stream);
    k_count<<<4096, 256, 0, stream>>>(ei, rowstart);
    k_scan1<<<SCAN_BLOCKS, 256, 0, stream>>>(rowstart, bsums);
    k_scan2<<<1, 64, 0, stream>>>(bsums, SCAN_BLOCKS);
    k_scan3<<<SCAN_BLOCKS, 256, 0, stream>>>(rowstart, bsums);
    k_fill<<<4096, 256, 0, stream>>>(ei, rowstart, cursor, csr);

    // ---- layer 1 ----
    k_agg_bf<<<AGG_BLOCKS, 256, 0, stream>>>(Xb, rowstart, csr, Ab);
    k_gemm_mfma<<<GEMM_BLOCKS, 256, 0, stream>>>(Ab, Xb, Wc1, b1, Ab);
    hipMemsetAsync(colsum, 0, sizeof(float) * 256, stream);
    k_colstats_bf<<<304, 256, 0, stream>>>(Ab, colsum, colsumsq);
    k_bnfin<<<1, 128, 0, stream>>>(colsum, colsumsq, g1, be1, scaleS, shiftS);
    k_bnrelu_bf<<<2048, 256, 0, stream>>>(Ab, scaleS, shiftS);

    // ---- layer 2 ----
    k_agg_bf<<<AGG_BLOCKS, 256, 0, stream>>>(Ab, rowstart, csr, Bb);
    k_gemm_mfma<<<GEMM_BLOCKS, 256, 0, stream>>>(Bb, Ab, Wc2, b2, Bb);
    hipMemsetAsync(colsum, 0, sizeof(float) * 256, stream);
    k_colstats_bf<<<304, 256, 0, stream>>>(Bb, colsum, colsumsq);
    k_bnfin<<<1, 128, 0, stream>>>(colsum, colsumsq, g2, be2, scaleS, shiftS);
    k_bnrelu_bf<<<2048, 256, 0, stream>>>(Bb, scaleS, shiftS);

    // ---- layer 3 (bias + log_softmax fused) ----
    k_agg_bf<<<AGG_BLOCKS, 256, 0, stream>>>(Bb, rowstart, csr, Ab);
    k_gemm40_mfma<<<GEMM_BLOCKS, 256, 0, stream>>>(Ab, Bb, Wc3, b3, out);
}

// Round 4
// 546.454 us; speedup vs baseline: 2.2481x; 1.0865x over previous
//
#include <hip/hip_runtime.h>
#include <cstdint>
#include <cstddef>
#include <math.h>

#define N_NODES 100000
#define N_EDGES 1600000
#define DIM 128
#define DOUT 40
#define BN_EPS 1e-5f

typedef __attribute__((ext_vector_type(8))) short bf16x8;
typedef __attribute__((ext_vector_type(4))) float f32x4;

__device__ __forceinline__ float bf2f(uint u16shifted) {
    union { uint i; float f; } c; c.i = u16shifted; return c.f;
}
__device__ __forceinline__ ushort f2bf(float f) {
    union { float f; uint i; } c; c.f = f;
    uint i = c.i;
    uint lsb = (i >> 16) & 1u;
    i += 0x7FFFu + lsb;
    return (ushort)(i >> 16);
}

// ---------------- convert x -> bf16 ----------------
__global__ __launch_bounds__(256) void k_cvt(const float* __restrict__ in,
                                             ushort* __restrict__ out, int n4) {
    int i = blockIdx.x * blockDim.x + threadIdx.x;
    int stride = gridDim.x * blockDim.x;
    for (; i < n4; i += stride) {
        float4 v = reinterpret_cast<const float4*>(in)[i];
        ushort4 o;
        o.x = f2bf(v.x); o.y = f2bf(v.y); o.z = f2bf(v.z); o.w = f2bf(v.w);
        reinterpret_cast<ushort4*>(out)[i] = o;
    }
}

// ---------------- build Wcat[n][k] = k<128 ? W[k][n] : R[k-128][n], bf16, zero-pad n>=NW ----
__global__ void k_wcat(const float* __restrict__ W, const float* __restrict__ R,
                       ushort* __restrict__ out, int NW) {
    int idx = blockIdx.x * 256 + threadIdx.x;  // grid = Nout blocks
    int n = idx >> 8, k = idx & 255;
    float v = 0.f;
    if (n < NW) v = (k < 128) ? W[k * NW + n] : R[(k - 128) * NW + n];
    out[idx] = f2bf(v);
}

// ---------------- CSR build, dst-range partitioned (8 groups ~ XCDs) ----------------
// group g = blockIdx & 7 handles only dst in [g*12500, (g+1)*12500); each group's
// blocks collectively sweep the whole edge list (chunk = blockIdx >> 3).
#define RANGE_SZ (N_NODES / 8)          // 12500
#define FILL_CHUNKS 128                  // blocks per group
#define EDGES_PER_CHUNK (N_EDGES / FILL_CHUNKS)  // 12500

__global__ __launch_bounds__(256) void k_count_p(const int* __restrict__ ei,
                                                 int* __restrict__ counts) {
    int g = blockIdx.x & 7;
    int chunk = blockIdx.x >> 3;
    int lo = g * RANGE_SZ, hi = lo + RANGE_SZ;
    int e0 = chunk * EDGES_PER_CHUNK, e1 = e0 + EDGES_PER_CHUNK;
    for (int e = e0 + threadIdx.x; e < e1; e += 256) {
        int d = ei[N_EDGES + e];
        if (d >= lo && d < hi) atomicAdd(&counts[d], 1);
    }
}

__global__ __launch_bounds__(256) void k_fill_p(const int* __restrict__ ei,
                                                int* __restrict__ cursor,
                                                int* __restrict__ csr) {
    int g = blockIdx.x & 7;
    int chunk = blockIdx.x >> 3;
    int lo = g * RANGE_SZ, hi = lo + RANGE_SZ;
    int e0 = chunk * EDGES_PER_CHUNK, e1 = e0 + EDGES_PER_CHUNK;
    for (int e = e0 + threadIdx.x; e < e1; e += 256) {
        int d = ei[N_EDGES + e];
        if (d >= lo && d < hi) {
            int s = ei[e];
            int pos = atomicAdd(&cursor[d], 1);  // cursor pre-loaded with rowstart
            csr[pos] = s;
        }
    }
}

__global__ void k_scan1(int* __restrict__ data, int* __restrict__ bsums) {
    __shared__ int ts[256];
    int base = blockIdx.x * 1024;
    int t = threadIdx.x;
    int v[4]; int s = 0;
#pragma unroll
    for (int i = 0; i < 4; i++) {
        int idx = base + t * 4 + i;
        v[i] = (idx < N_NODES) ? data[idx] : 0;
        s += v[i];
    }
    ts[t] = s; __syncthreads();
    for (int off = 1; off < 256; off <<= 1) {
        int own = ts[t];
        int add = (t >= off) ? ts[t - off] : 0;
        __syncthreads();
        ts[t] = own + add;
        __syncthreads();
    }
    int incl = ts[t];
    int run = incl - s;
#pragma unroll
    for (int i = 0; i < 4; i++) {
        int idx = base + t * 4 + i;
        if (idx < N_NODES) data[idx] = run;
        run += v[i];
    }
    if (t == 255) bsums[blockIdx.x] = incl;
}

__global__ void k_scan2(int* bsums, int nb) {
    if (threadIdx.x == 0) {
        int run = 0;
        for (int b = 0; b < nb; b++) { int x = bsums[b]; bsums[b] = run; run += x; }
    }
}

__global__ void k_scan3(int* __restrict__ data, const int* __restrict__ bsums) {
    int base = blockIdx.x * 1024;
    int add = bsums[blockIdx.x];
    int t = threadIdx.x;
#pragma unroll
    for (int i = 0; i < 4; i++) {
        int idx = base + t * 4 + i;
        if (idx < N_NODES) data[idx] += add;
    }
    if (blockIdx.x == 0 && t == 0) data[N_NODES] = N_EDGES;
}

// ---------------- mean aggregation, bf16, 4 edges in flight ----------------
// one wave per node; lane = slot(0..3) x colgroup(0..15); each lane loads uint4 = 8 bf16 cols
__global__ __launch_bounds__(256) void k_agg_bf(const ushort* __restrict__ cur,
                                                const int* __restrict__ rowstart,
                                                const int* __restrict__ csr,
                                                ushort* __restrict__ out) {
    int wid = (blockIdx.x * blockDim.x + threadIdx.x) >> 6;
    int lane = threadIdx.x & 63;
    if (wid >= N_NODES) return;
    int beg = rowstart[wid];
    int end = rowstart[wid + 1];
    int slot = lane >> 4;   // which edge within a group of 4
    int cg = lane & 15;     // column group: cols cg*8 .. cg*8+7
    const uint4* base = reinterpret_cast<const uint4*>(cur);  // row = 16 x uint4
    float a0 = 0.f, a1 = 0.f, a2 = 0.f, a3 = 0.f, a4 = 0.f, a5 = 0.f, a6 = 0.f, a7 = 0.f;
#pragma unroll 2
    for (int e = beg + slot; e < end; e += 4) {
        int s = csr[e];
        uint4 u = base[(size_t)s * 16 + cg];
        a0 += bf2f(u.x << 16); a1 += bf2f(u.x & 0xFFFF0000u);
        a2 += bf2f(u.y << 16); a3 += bf2f(u.y & 0xFFFF0000u);
        a4 += bf2f(u.z << 16); a5 += bf2f(u.z & 0xFFFF0000u);
        a6 += bf2f(u.w << 16); a7 += bf2f(u.w & 0xFFFF0000u);
    }
    // combine the 4 slots: lanes l, l^16, l^32
#pragma unroll
    for (int off = 16; off < 64; off <<= 1) {
        a0 += __shfl_xor(a0, off, 64); a1 += __shfl_xor(a1, off, 64);
        a2 += __shfl_xor(a2, off, 64); a3 += __shfl_xor(a3, off, 64);
        a4 += __shfl_xor(a4, off, 64); a5 += __shfl_xor(a5, off, 64);
        a6 += __shfl_xor(a6, off, 64); a7 += __shfl_xor(a7, off, 64);
    }
    if (slot == 0) {
        int deg = end - beg;
        float inv = 1.0f / (float)(deg > 1 ? deg : 1);
        uint4 o;
        o.x = (uint)f2bf(a0 * inv) | ((uint)f2bf(a1 * inv) << 16);
        o.y = (uint)f2bf(a2 * inv) | ((uint)f2bf(a3 * inv) << 16);
        o.z = (uint)f2bf(a4 * inv) | ((uint)f2bf(a5 * inv) << 16);
        o.w = (uint)f2bf(a6 * inv) | ((uint)f2bf(a7 * inv) << 16);
        reinterpret_cast<uint4*>(out)[(size_t)wid * 16 + cg] = o;
    }
}

// ---------------- MFMA GEMM: out[M,128] = mean@W + cur@R + b (bf16 in, bf16 out) ------------
// 128x128 tile, 256 threads = 4 waves as 2x2, each wave 64x64 (4x4 frags of 16x16x32)
// in-place safe for out==mean (block reads only its own rows; writes in epilogue)
__global__ __launch_bounds__(256) void k_gemm_mfma(const ushort* __restrict__ Am,
                                                   const ushort* __restrict__ Ac,
                                                   const ushort* __restrict__ Wcat, // [128][256]
                                                   const float* __restrict__ bias,
                                                   ushort* __restrict__ out) {
    __shared__ ushort As[128 * 40];  // 128 rows x 32 k, padded stride 40 (80 B)
    __shared__ ushort Bs[128 * 40];  // 128 cols x 32 k
    int tid = threadIdx.x;
    int wid = tid >> 6, lane = tid & 63;
    int wr = wid >> 1, wc = wid & 1;
    int l15 = lane & 15, lhi = lane >> 4;
    int row0 = blockIdx.x * 128;

    f32x4 acc[4][4];
#pragma unroll
    for (int m = 0; m < 4; m++)
#pragma unroll
        for (int n = 0; n < 4; n++) acc[m][n] = (f32x4){0.f, 0.f, 0.f, 0.f};

    for (int ks = 0; ks < 8; ++ks) {
        int kg = ks * 32;
        const ushort* Asrc = (kg < 128) ? Am : Ac;
        int ka = kg & 127;
        __syncthreads();
#pragma unroll
        for (int h = 0; h < 2; ++h) {
            int c = tid + h * 256;
            int row = c >> 2, q = c & 3;
            int gr = row0 + row;
            uint4 v = {0, 0, 0, 0};
            if (gr < N_NODES)
                v = *reinterpret_cast<const uint4*>(Asrc + (size_t)gr * 128 + ka + q * 8);
            *reinterpret_cast<uint4*>(&As[row * 40 + q * 8]) = v;
        }
#pragma unroll
        for (int h = 0; h < 2; ++h) {
            int c = tid + h * 256;
            int n = c >> 2, q = c & 3;
            *reinterpret_cast<uint4*>(&Bs[n * 40 + q * 8]) =
                *reinterpret_cast<const uint4*>(Wcat + n * 256 + kg + q * 8);
        }
        __syncthreads();
        bf16x8 a[4], b[4];
#pragma unroll
        for (int m = 0; m < 4; m++)
            a[m] = *reinterpret_cast<bf16x8*>(&As[(wr * 64 + m * 16 + l15) * 40 + lhi * 8]);
#pragma unroll
        for (int n = 0; n < 4; n++)
            b[n] = *reinterpret_cast<bf16x8*>(&Bs[(wc * 64 + n * 16 + l15) * 40 + lhi * 8]);
#pragma unroll
        for (int m = 0; m < 4; m++)
#pragma unroll
            for (int n = 0; n < 4; n++)
                acc[m][n] = __builtin_amdgcn_mfma_f32_16x16x32_bf16(a[m], b[n], acc[m][n], 0, 0, 0);
    }
    // epilogue: + bias, bf16 store
#pragma unroll
    for (int m = 0; m < 4; m++) {
        int rbase = row0 + wr * 64 + m * 16 + lhi * 4;
#pragma unroll
        for (int n = 0; n < 4; n++) {
            int col = wc * 64 + n * 16 + l15;
            float bv = bias[col];
#pragma unroll
            for (int j = 0; j < 4; j++) {
                int gr = rbase + j;
                if (gr < N_NODES) out[(size_t)gr * 128 + col] = f2bf(acc[m][n][j] + bv);
            }
        }
    }
}

// ---------------- layer-3 MFMA GEMM + bias + log_softmax fused ----------------
// 128 rows x 48 cols (40 padded to 48); 4 waves, wave w: rows w*32..+31 (2 frags), 3 col frags
__global__ __launch_bounds__(256) void k_gemm40_mfma(const ushort* __restrict__ Am,
                                                     const ushort* __restrict__ Ac,
                                                     const ushort* __restrict__ Wcat, // [48][256]
                                                     const float* __restrict__ bias,  // [40]
                                                     float* __restrict__ out) {
    __shared__ ushort As[128 * 40];
    __shared__ ushort Bs[48 * 40];
    int tid = threadIdx.x;
    int w = tid >> 6, lane = tid & 63;
    int l15 = lane & 15, lhi = lane >> 4;
    int row0 = blockIdx.x * 128;

    f32x4 acc[2][3];
#pragma unroll
    for (int m = 0; m < 2; m++)
#pragma unroll
        for (int n = 0; n < 3; n++) acc[m][n] = (f32x4){0.f, 0.f, 0.f, 0.f};

    for (int ks = 0; ks < 8; ++ks) {
        int kg = ks * 32;
        const ushort* Asrc = (kg < 128) ? Am : Ac;
        int ka = kg & 127;
        __syncthreads();
#pragma unroll
        for (int h = 0; h < 2; ++h) {
            int c = tid + h * 256;
            int row = c >> 2, q = c & 3;
            int gr = row0 + row;
            uint4 v = {0, 0, 0, 0};
            if (gr < N_NODES)
                v = *reinterpret_cast<const uint4*>(Asrc + (size_t)gr * 128 + ka + q * 8);
            *reinterpret_cast<uint4*>(&As[row * 40 + q * 8]) = v;
        }
        if (tid < 192) {
            int n = tid >> 2, q = tid & 3;
            *reinterpret_cast<uint4*>(&Bs[n * 40 + q * 8]) =
                *reinterpret_cast<const uint4*>(Wcat + n * 256 + kg + q * 8);
        }
        __syncthreads();
        bf16x8 a[2], b[3];
#pragma unroll
        for (int m = 0; m < 2; m++)
            a[m] = *reinterpret_cast<bf16x8*>(&As[(w * 32 + m * 16 + l15) * 40 + lhi * 8]);
#pragma unroll
        for (int n = 0; n < 3; n++)
            b[n] = *reinterpret_cast<bf16x8*>(&Bs[(n * 16 + l15) * 40 + lhi * 8]);
#pragma unroll
        for (int m = 0; m < 2; m++)
#pragma unroll
            for (int n = 0; n < 3; n++)
                acc[m][n] = __builtin_amdgcn_mfma_f32_16x16x32_bf16(a[m], b[n], acc[m][n], 0, 0, 0);
    }
    // epilogue: bias + log_softmax per row (row lives in a 16-lane group)
    float b0 = bias[l15];
    float b1 = bias[16 + l15];
    float b2 = (l15 < 8) ? bias[32 + l15] : 0.f;
#pragma unroll
    for (int m = 0; m < 2; m++) {
#pragma unroll
        for (int j = 0; j < 4; j++) {
            int grow = row0 + w * 32 + m * 16 + lhi * 4 + j;
            float v0 = acc[m][0][j] + b0;
            float v1 = acc[m][1][j] + b1;
            float v2 = (l15 < 8) ? (acc[m][2][j] + b2) : -INFINITY;
            float mx = fmaxf(fmaxf(v0, v1), v2);
#pragma unroll
            for (int off = 1; off < 16; off <<= 1) mx = fmaxf(mx, __shfl_xor(mx, off, 64));
            float s = expf(v0 - mx) + expf(v1 - mx) + ((l15 < 8) ? expf(v2 - mx) : 0.f);
#pragma unroll
            for (int off = 1; off < 16; off <<= 1) s += __shfl_xor(s, off, 64);
            float lg = mx + logf(s);
            if (grow < N_NODES) {
                out[(size_t)grow * DOUT + l15] = v0 - lg;
                out[(size_t)grow * DOUT + 16 + l15] = v1 - lg;
                if (l15 < 8) out[(size_t)grow * DOUT + 32 + l15] = v2 - lg;
            }
        }
    }
}

// ---------------- BN stats on bf16 H ----------------
__global__ __launch_bounds__(256) void k_colstats_bf(const ushort* __restrict__ H,
                                                     float* __restrict__ sum,
                                                     float* __restrict__ sumsq) {
    int tid = threadIdx.x;
    int cg = tid & 31;   // cols cg*4..cg*4+3
    int rr = tid >> 5;   // 0..7
    float s[4] = {0, 0, 0, 0}, s2[4] = {0, 0, 0, 0};
    for (int r = blockIdx.x * 8 + rr; r < N_NODES; r += gridDim.x * 8) {
        uint2 u = *reinterpret_cast<const uint2*>(H + (size_t)r * 128 + cg * 4);
        float f0 = bf2f(u.x << 16), f1 = bf2f(u.x & 0xFFFF0000u);
        float f2 = bf2f(u.y << 16), f3 = bf2f(u.y & 0xFFFF0000u);
        s[0] += f0; s2[0] += f0 * f0;
        s[1] += f1; s2[1] += f1 * f1;
        s[2] += f2; s2[2] += f2 * f2;
        s[3] += f3; s2[3] += f3 * f3;
    }
    __shared__ float ls[256][4], ls2[256][4];
#pragma unroll
    for (int i = 0; i < 4; i++) { ls[tid][i] = s[i]; ls2[tid][i] = s2[i]; }
    __syncthreads();
    if (tid < 32) {
#pragma unroll
        for (int j = 1; j < 8; j++)
#pragma unroll
            for (int i = 0; i < 4; i++) { s[i] += ls[j * 32 + tid][i]; s2[i] += ls2[j * 32 + tid][i]; }
#pragma unroll
        for (int i = 0; i < 4; i++) {
            atomicAdd(&sum[tid * 4 + i], s[i]);
            atomicAdd(&sumsq[tid * 4 + i], s2[i]);
        }
    }
}

__global__ void k_bnfin(const float* __restrict__ sum, const float* __restrict__ sumsq,
                        const float* __restrict__ g, const float* __restrict__ be,
                        float* __restrict__ scale, float* __restrict__ shift) {
    int c = threadIdx.x;
    if (c < DIM) {
        float mu = sum[c] * (1.0f / N_NODES);
        float var = sumsq[c] * (1.0f / N_NODES) - mu * mu;
        float sc = g[c] * rsqrtf(var + BN_EPS);
        scale[c] = sc;
        shift[c] = be[c] - mu * sc;
    }
}

// ---------------- BN apply + ReLU, bf16 in-place ----------------
__global__ __launch_bounds__(256) void k_bnrelu_bf(ushort* __restrict__ H,
                                                   const float* __restrict__ scale,
                                                   const float* __restrict__ shift) {
    __shared__ float sc[128], sh[128];
    int tid = threadIdx.x;
    if (tid < 128) { sc[tid] = scale[tid]; sh[tid] = shift[tid]; }
    __syncthreads();
    int i = blockIdx.x * blockDim.x + tid;
    int stride = gridDim.x * blockDim.x;
    int total = N_NODES * (DIM / 4);  // uint2 units
    uint2* H2 = reinterpret_cast<uint2*>(H);
    for (; i < total; i += stride) {
        uint2 u = H2[i];
        int c = (i & 31) * 4;
        float f0 = fmaxf(bf2f(u.x << 16) * sc[c + 0] + sh[c + 0], 0.f);
        float f1 = fmaxf(bf2f(u.x & 0xFFFF0000u) * sc[c + 1] + sh[c + 1], 0.f);
        float f2 = fmaxf(bf2f(u.y << 16) * sc[c + 2] + sh[c + 2], 0.f);
        float f3 = fmaxf(bf2f(u.y & 0xFFFF0000u) * sc[c + 3] + sh[c + 3], 0.f);
        u.x = (uint)f2bf(f0) | ((uint)f2bf(f1) << 16);
        u.y = (uint)f2bf(f2) | ((uint)f2bf(f3) << 16);
        H2[i] = u;
    }
}

// ---------------- launch ----------------
extern "C" void kernel_launch(void* const* d_in, const int* in_sizes, int n_in,
                              void* d_out, int out_size, void* d_ws, size_t ws_size,
                              hipStream_t stream) {
    const float* x = (const float*)d_in[0];
    const int* ei = (const int*)d_in[1];
    const float* w1 = (const float*)d_in[2];
    const float* r1 = (const float*)d_in[3];
    const float* b1 = (const float*)d_in[4];
    const float* g1 = (const float*)d_in[5];
    const float* be1 = (const float*)d_in[6];
    const float* w2 = (const float*)d_in[7];
    const float* r2 = (const float*)d_in[8];
    const float* b2 = (const float*)d_in[9];
    const float* g2 = (const float*)d_in[10];
    const float* be2 = (const float*)d_in[11];
    const float* w3 = (const float*)d_in[12];
    const float* r3 = (const float*)d_in[13];
    const float* b3 = (const float*)d_in[14];
    float* out = (float*)d_out;

    const size_t NF = (size_t)N_NODES * DIM;  // 12.8M
    ushort* Xb = (ushort*)d_ws;
    ushort* Ab = Xb + NF;
    ushort* Bb = Ab + NF;
    ushort* Wc1 = Bb + NF;             // 128*256
    ushort* Wc2 = Wc1 + 128 * 256;
    ushort* Wc3 = Wc2 + 128 * 256;     // 48*256
    int* rowstart = (int*)(Wc3 + 48 * 256);
    int* csr = rowstart + (N_NODES + 1);
    int* cursor = csr + N_EDGES;
    int* bsums = cursor + N_NODES;
    float* colsum = (float*)(bsums + 128);
    float* colsumsq = colsum + 128;
    float* scaleS = colsumsq + 128;
    float* shiftS = scaleS + 128;
    size_t needed = (size_t)((char*)(shiftS + 128) - (char*)d_ws);
    if (ws_size < needed) return;

    const int SCAN_BLOCKS = (N_NODES + 1023) / 1024;  // 98
    const int AGG_BLOCKS = N_NODES / 4;               // 25000
    const int GEMM_BLOCKS = (N_NODES + 127) / 128;    // 782
    const int FILL_BLOCKS = FILL_CHUNKS * 8;          // 1024

    // conversions
    k_cvt<<<2048, 256, 0, stream>>>(x, Xb, (int)(NF / 4));
    k_wcat<<<128, 256, 0, stream>>>(w1, r1, Wc1, 128);
    k_wcat<<<128, 256, 0, stream>>>(w2, r2, Wc2, 128);
    k_wcat<<<48, 256, 0, stream>>>(w3, r3, Wc3, DOUT);

    // CSR build (dst-range partitioned)
    hipMemsetAsync(rowstart, 0, sizeof(int) * (N_NODES + 1), stream);
    k_count_p<<<FILL_BLOCKS, 256, 0, stream>>>(ei, rowstart);
    k_scan1<<<SCAN_BLOCKS, 256, 0, stream>>>(rowstart, bsums);
    k_scan2<<<1, 64, 0, stream>>>(bsums, SCAN_BLOCKS);
    k_scan3<<<SCAN_BLOCKS, 256, 0, stream>>>(rowstart, bsums);
    hipMemcpyAsync(cursor, rowstart, sizeof(int) * N_NODES, hipMemcpyDeviceToDevice, stream);
    k_fill_p<<<FILL_BLOCKS, 256, 0, stream>>>(ei, cursor, csr);

    // ---- layer 1 ----
    k_agg_bf<<<AGG_BLOCKS, 256, 0, stream>>>(Xb, rowstart, csr, Ab);
    k_gemm_mfma<<<GEMM_BLOCKS, 256, 0, stream>>>(Ab, Xb, Wc1, b1, Ab);
    hipMemsetAsync(colsum, 0, sizeof(float) * 256, stream);
    k_colstats_bf<<<304, 256, 0, stream>>>(Ab, colsum, colsumsq);
    k_bnfin<<<1, 128, 0, stream>>>(colsum, colsumsq, g1, be1, scaleS, shiftS);
    k_bnrelu_bf<<<2048, 256, 0, stream>>>(Ab, scaleS, shiftS);

    // ---- layer 2 ----
    k_agg_bf<<<AGG_BLOCKS, 256, 0, stream>>>(Ab, rowstart, csr, Bb);
    k_gemm_mfma<<<GEMM_BLOCKS, 256, 0, stream>>>(Bb, Ab, Wc2, b2, Bb);
    hipMemsetAsync(colsum, 0, sizeof(float) * 256, stream);
    k_colstats_bf<<<304, 256, 0, stream>>>(Bb, colsum, colsumsq);
    k_bnfin<<<1, 128, 0, stream>>>(colsum, colsumsq, g2, be2, scaleS, shiftS);
    k_bnrelu_bf<<<2048, 256, 0, stream>>>(Bb, scaleS, shiftS);

    // ---- layer 3 (bias + log_softmax fused) ----
    k_agg_bf<<<AGG_BLOCKS, 256, 0, stream>>>(Bb, rowstart, csr, Ab);
    k_gemm40_mfma<<<GEMM_BLOCKS, 256, 0, stream>>>(Ab, Bb, Wc3, b3, out);
}